// Round 4
// baseline (595.749 us; speedup 1.0000x reference)
//
#include <hip/hip_runtime.h>
#include <math.h>

// ---------------- problem constants ----------------
#define BATCH   4096
#define NUM     13
#define NCAT    26
#define VOCAB   1000
#define EMB     16
#define DEMBED  624      // NUM*EMB + NCAT*EMB = 208 + 416
#define KPAD    640      // DEMBED padded to multiple of 64 for BK=64 MFMA loop
#define H1      512
#define H2      256

#define LDS_STRIDE 72    // 64 + 8 ushorts pad: 144 B rows, 2-way max conflict (free)

typedef unsigned short ushort_t;
typedef __attribute__((ext_vector_type(8))) short bf16x8;
typedef __attribute__((ext_vector_type(4))) float f32x4;

// ---------------- workspace layout (bytes) ----------------
#define WS_YFM_OFF    0                                    // f32  4096      = 16384
#define WS_YDEEP_OFF  (WS_YFM_OFF + BATCH * 4)             // f32  4096      = 16384
#define WS_EMBED_OFF  (WS_YDEEP_OFF + BATCH * 4)           // bf16 4096*640  = 5242880
#define WS_H1_OFF     (WS_EMBED_OFF + BATCH * KPAD * 2)    // bf16 4096*512  = 4194304
#define WS_W1T_OFF    (WS_H1_OFF + BATCH * H1 * 2)         // bf16 512*640   = 655360
#define WS_W2T_OFF    (WS_W1T_OFF + H1 * KPAD * 2)         // bf16 256*512   = 262144

__device__ __forceinline__ ushort_t f2bf(float f) {
    union { float f; unsigned int u; } v; v.f = f;
    unsigned int r = v.u + 0x7FFFu + ((v.u >> 16) & 1u);   // round-nearest-even
    return (ushort_t)(r >> 16);
}

// ---------------------------------------------------------------------------
// Kernel A+B merged: blocks [0, BATCH) do the fused one-hot scan + assembly
// (one block per sample); blocks [BATCH, ...) do weight prep (W1/W2
// cast+transpose, ydeep zero-init).
//
// Scan: BREADTH-FIRST across each wave's 6-7 categories at 64-elem (256 B)
// granularity — one coalesced float per lane. Per phase: issue one load per
// UNFOUND category (6-7 independent loads in flight), then ballot-check each.
// Bytes and latency are decoupled by the breadth-first order:
// E[bytes] = 531.5/1000 * 426 MB = 227 MB (floor is 213 MB), round-trips
// pipelined across categories, hidden by ~8 resident blocks/CU TLP.
// ---------------------------------------------------------------------------
#define PREP_N1 (H1 * KPAD)          // 327680
#define PREP_N2 (H2 * H1)            // 131072
#define PREP_N3 (BATCH)              // ydeep zeroes
#define PREP_TOTAL (PREP_N1 + PREP_N2 + PREP_N3)
#define PREP_BLOCKS ((PREP_TOTAL + 255) / 256)

__global__ __launch_bounds__(256) void scan_prep_kernel(
    const float* __restrict__ cat,
    const float* __restrict__ numeric, const float* __restrict__ W_num,
    const float* __restrict__ b_num, const float* __restrict__ emb_tables,
    const float* __restrict__ w_fm, const float* __restrict__ b_fm,
    ushort_t* __restrict__ embedB, float* __restrict__ yfm,
    const float* __restrict__ W1, const float* __restrict__ W2,
    ushort_t* __restrict__ W1t, ushort_t* __restrict__ W2t,
    float* __restrict__ ydeep)
{
    __shared__ float es[DEMBED];
    __shared__ int   lab[NCAT];
    __shared__ float red[EMB];
    __shared__ float sp[NCAT + NUM];

    int tid = threadIdx.x;

    // ---------------- prep blocks ----------------
    if (blockIdx.x >= BATCH) {
        int t = (blockIdx.x - BATCH) * 256 + tid;
        if (t < PREP_N1) {
            int n = t / KPAD, kp = t - n * KPAD;
            float v = (kp < DEMBED) ? W1[(size_t)kp * H1 + n] : 0.f;
            W1t[t] = f2bf(v);
        } else if (t < PREP_N1 + PREP_N2) {
            int u = t - PREP_N1;
            int n = u >> 9, k = u & 511;
            W2t[u] = f2bf(W2[(size_t)k * H2 + n]);
        } else if (t < PREP_TOTAL) {
            ydeep[t - PREP_N1 - PREP_N2] = 0.f;
        }
        return;
    }

    // ---------------- scan blocks ----------------
    int b    = blockIdx.x;
    int w    = tid >> 6;
    int lane = tid & 63;

    // wave w owns cats {w, w+4, w+8, ...}: 7 for w<2, 6 for w>=2
    {
        const int nc = (w < 2) ? 7 : 6;
        int labf[7];
#pragma unroll
        for (int i = 0; i < 7; ++i) labf[i] = -1;
        unsigned mask = (1u << nc) - 1;      // unfound cats (wave-uniform)

        for (int p = 0; p < 16 && mask; ++p) {
            float v[7];
            int idx = p * 64 + lane;         // element index within row
            bool inb = idx < VOCAB;
#pragma unroll
            for (int i = 0; i < 7; ++i) {
                if (i < nc && ((mask >> i) & 1)) {
                    int c = w + 4 * i;
                    const float* src = cat + ((size_t)b * NCAT + c) * VOCAB;
                    v[i] = inb ? src[idx] : 0.f;
                }
            }
#pragma unroll
            for (int i = 0; i < 7; ++i) {
                if (i < nc && ((mask >> i) & 1)) {
                    int f = (v[i] > 0.5f) ? idx : -1;
                    unsigned long long bal = __ballot(f >= 0);
                    if (bal) {
                        int src_lane = (int)__ffsll((unsigned long long)bal) - 1;
                        labf[i] = __shfl(f, src_lane);
                        mask &= ~(1u << i);
                    }
                }
            }
        }
        if (lane == 0) {
#pragma unroll
            for (int i = 0; i < 7; ++i)
                if (i < nc) lab[w + 4 * i] = (labf[i] < 0) ? 0 : labf[i];
        }
    }
    __syncthreads();

    // ---- assemble embed row (bf16, KPAD wide) ----
    ushort_t* eout = embedB + (size_t)b * KPAD;
    for (int t = tid; t < KPAD; t += 256) {
        float v = 0.f;
        if (t < NUM * EMB) {
            int j = t >> 4;
            v = numeric[b * NUM + j] * W_num[t] + b_num[t];
        } else if (t < DEMBED) {
            int u = t - NUM * EMB;
            int c = u >> 4, k = u & 15;
            v = emb_tables[((size_t)c * VOCAB + lab[c]) * EMB + k];
        }
        if (t < DEMBED) es[t] = v;
        eout[t] = f2bf(v);
    }
    // parallel sparse-FM gathers
    if (tid < NCAT) {
        sp[tid] = w_fm[NUM + tid * VOCAB + lab[tid]];
    } else if (tid < NCAT + NUM) {
        int j = tid - NCAT;
        sp[tid] = numeric[b * NUM + j] * w_fm[j];
    }
    __syncthreads();

    if (tid < EMB) {
        float ns = 0.f, cs = 0.f;
        for (int j = 0; j < NUM; ++j)  ns += es[j * EMB + tid];
        for (int c = 0; c < NCAT; ++c) cs += es[NUM * EMB + c * EMB + tid];
        red[tid] = ns * cs;
    }
    __syncthreads();

    if (tid == 0) {
        float y = b_fm[0];
        for (int k = 0; k < EMB; ++k)          y += red[k];
        for (int i = 0; i < NCAT + NUM; ++i)   y += sp[i];
        yfm[b] = y;
    }
}

// ---------------------------------------------------------------------------
// Kernel C: MFMA bf16 GEMM1: h1 = relu(embed @ W1t^T + b1) -> bf16.
// 64x64 tile, BK=64, 4 waves (2x2), each wave 32x32 via 2x2 mfma 16x16x32.
// k+1 global loads issued after the second barrier (overlap the MFMA phase).
// Fragment layouts (HW-verified):
//   A/B-op: lane holds X[m=lane&15][k=(lane>>4)*8 + j], j=0..7
//   C/D   : col=lane&15, row=(lane>>4)*4 + reg
// ---------------------------------------------------------------------------
__global__ __launch_bounds__(256) void gemm1_kernel(
    const ushort_t* __restrict__ A, const ushort_t* __restrict__ Bt,
    const float* __restrict__ bias, ushort_t* __restrict__ Cout)
{
    const int N = H1, K = KPAD;
    __shared__ ushort_t As[64 * LDS_STRIDE];
    __shared__ ushort_t Bs[64 * LDS_STRIDE];

    int tid = threadIdx.x;
    int l   = tid & 63;
    int w   = tid >> 6;
    int wm  = w >> 1, wn = w & 1;
    int bm  = blockIdx.y * 64;
    int bn  = blockIdx.x * 64;

    int srow = tid >> 2;
    int sk   = (tid & 3) * 8;

    const ushort_t* ap = &A [(size_t)(bm + srow) * K + sk];
    const ushort_t* bp = &Bt[(size_t)(bn + srow) * K + sk];

    // prologue: prefetch k0 = 0
    uint4 av0 = *(const uint4*)ap;
    uint4 av1 = *(const uint4*)(ap + 32);
    uint4 bv0 = *(const uint4*)bp;
    uint4 bv1 = *(const uint4*)(bp + 32);

    f32x4 acc[2][2];
#pragma unroll
    for (int i = 0; i < 2; ++i)
#pragma unroll
        for (int j = 0; j < 2; ++j)
            acc[i][j] = (f32x4){0.f, 0.f, 0.f, 0.f};

    for (int k0 = 0; k0 < K; k0 += 64) {
        __syncthreads();                      // LDS free (prev iter reads done)
        *(uint4*)&As[srow * LDS_STRIDE + sk]      = av0;
        *(uint4*)&As[srow * LDS_STRIDE + sk + 32] = av1;
        *(uint4*)&Bs[srow * LDS_STRIDE + sk]      = bv0;
        *(uint4*)&Bs[srow * LDS_STRIDE + sk + 32] = bv1;
        __syncthreads();

        if (k0 + 64 < K) {                    // prefetch k+1 under MFMA phase
            av0 = *(const uint4*)(ap + k0 + 64);
            av1 = *(const uint4*)(ap + k0 + 96);
            bv0 = *(const uint4*)(bp + k0 + 64);
            bv1 = *(const uint4*)(bp + k0 + 96);
        }

#pragma unroll
        for (int s = 0; s < 2; ++s) {
            bf16x8 af[2], bfr[2];
#pragma unroll
            for (int i = 0; i < 2; ++i)
                af[i] = *(const bf16x8*)&As[(wm * 32 + i * 16 + (l & 15)) * LDS_STRIDE
                                            + s * 32 + (l >> 4) * 8];
#pragma unroll
            for (int j = 0; j < 2; ++j)
                bfr[j] = *(const bf16x8*)&Bs[(wn * 32 + j * 16 + (l & 15)) * LDS_STRIDE
                                             + s * 32 + (l >> 4) * 8];
#pragma unroll
            for (int i = 0; i < 2; ++i)
#pragma unroll
                for (int j = 0; j < 2; ++j)
                    acc[i][j] = __builtin_amdgcn_mfma_f32_16x16x32_bf16(
                        af[i], bfr[j], acc[i][j], 0, 0, 0);
        }
    }

#pragma unroll
    for (int i = 0; i < 2; ++i) {
        int row0 = bm + wm * 32 + i * 16 + (l >> 4) * 4;
#pragma unroll
        for (int j = 0; j < 2; ++j) {
            int col = bn + wn * 32 + j * 16 + (l & 15);
            float bv = bias[col];
#pragma unroll
            for (int r = 0; r < 4; ++r) {
                float v = fmaxf(acc[i][j][r] + bv, 0.f);
                Cout[(size_t)(row0 + r) * N + col] = f2bf(v);
            }
        }
    }
}

// ---------------------------------------------------------------------------
// Kernel D: fused GEMM2 + W3 dot. h2 never materializes.
// 32x64 tile (grid 4 x 128 = 512 blocks), BK=64, 4 waves:
// wave w: row-tile i=w>>1 (16 rows), cols (w&1)*32 + 2x16.
// k+1 prefetch-under-MFMA as gemm1.
// Epilogue: s = sum_j relu(acc+b2)*W3[col]; 16-lane shuffle-reduce;
// atomicAdd into ydeep[row] (zeroed by prep). ReLU is per-element of h2,
// so N-split partial dots are exact.
// ---------------------------------------------------------------------------
__global__ __launch_bounds__(256) void gemm2_dot_kernel(
    const ushort_t* __restrict__ A, const ushort_t* __restrict__ Bt,
    const float* __restrict__ bias, const float* __restrict__ W3,
    float* __restrict__ ydeep)
{
    const int K = H1;
    __shared__ ushort_t As[32 * LDS_STRIDE];
    __shared__ ushort_t Bs[64 * LDS_STRIDE];

    int tid = threadIdx.x;
    int l   = tid & 63;
    int w   = tid >> 6;
    int it  = w >> 1;               // row-tile index (0..1)
    int cb  = (w & 1) * 32;         // col base within tile
    int bm  = blockIdx.y * 32;
    int bn  = blockIdx.x * 64;

    int srow = tid >> 3;            // 0..31
    int sk   = (tid & 7) * 8;       // 0..56

    const ushort_t* ap  = &A [(size_t)(bm + srow) * K + sk];
    const ushort_t* bp0 = &Bt[(size_t)(bn + srow) * K + sk];
    const ushort_t* bp1 = &Bt[(size_t)(bn + srow + 32) * K + sk];

    uint4 av  = *(const uint4*)ap;
    uint4 bv0 = *(const uint4*)bp0;
    uint4 bv1 = *(const uint4*)bp1;

    f32x4 acc[2];
    acc[0] = (f32x4){0.f, 0.f, 0.f, 0.f};
    acc[1] = (f32x4){0.f, 0.f, 0.f, 0.f};

    for (int k0 = 0; k0 < K; k0 += 64) {
        __syncthreads();
        *(uint4*)&As[srow * LDS_STRIDE + sk]        = av;
        *(uint4*)&Bs[srow * LDS_STRIDE + sk]        = bv0;
        *(uint4*)&Bs[(srow + 32) * LDS_STRIDE + sk] = bv1;
        __syncthreads();

        if (k0 + 64 < K) {                    // prefetch k+1 under MFMA phase
            av  = *(const uint4*)(ap  + k0 + 64);
            bv0 = *(const uint4*)(bp0 + k0 + 64);
            bv1 = *(const uint4*)(bp1 + k0 + 64);
        }

#pragma unroll
        for (int s = 0; s < 2; ++s) {
            bf16x8 af = *(const bf16x8*)&As[(it * 16 + (l & 15)) * LDS_STRIDE
                                            + s * 32 + (l >> 4) * 8];
#pragma unroll
            for (int j = 0; j < 2; ++j) {
                bf16x8 bfr = *(const bf16x8*)&Bs[(cb + j * 16 + (l & 15)) * LDS_STRIDE
                                                 + s * 32 + (l >> 4) * 8];
                acc[j] = __builtin_amdgcn_mfma_f32_16x16x32_bf16(af, bfr, acc[j], 0, 0, 0);
            }
        }
    }

    // epilogue: partial dot with W3 over this wave's 32 cols
    int row0 = bm + it * 16 + (l >> 4) * 4;
    float w3v[2], b2v[2];
#pragma unroll
    for (int j = 0; j < 2; ++j) {
        int col = bn + cb + j * 16 + (l & 15);
        w3v[j] = W3[col];
        b2v[j] = bias[col];
    }
#pragma unroll
    for (int r = 0; r < 4; ++r) {
        float s = fmaxf(acc[0][r] + b2v[0], 0.f) * w3v[0]
                + fmaxf(acc[1][r] + b2v[1], 0.f) * w3v[1];
#pragma unroll
        for (int off = 8; off > 0; off >>= 1)
            s += __shfl_xor(s, off);
        if ((l & 15) == 0)
            atomicAdd(&ydeep[row0 + r], s);
    }
}

// ---------------------------------------------------------------------------
// Kernel E: final: out = sigmoid(yfm + relu(ydeep + b3))
// ---------------------------------------------------------------------------
__global__ __launch_bounds__(256) void final_kernel(
    const float* __restrict__ yfm, const float* __restrict__ ydeep,
    const float* __restrict__ b3, float* __restrict__ out)
{
    int b = blockIdx.x * 256 + threadIdx.x;
    if (b >= BATCH) return;
    float yd = fmaxf(ydeep[b] + b3[0], 0.f);
    float x  = yfm[b] + yd;
    out[b] = 1.f / (1.f + expf(-x));
}

// ---------------------------------------------------------------------------
extern "C" void kernel_launch(void* const* d_in, const int* in_sizes, int n_in,
                              void* d_out, int out_size, void* d_ws, size_t ws_size,
                              hipStream_t stream)
{
    const float* numeric  = (const float*)d_in[0];
    const float* cat      = (const float*)d_in[1];
    const float* W_num    = (const float*)d_in[2];
    const float* b_num    = (const float*)d_in[3];
    const float* emb_tab  = (const float*)d_in[4];
    const float* w_fm     = (const float*)d_in[5];
    const float* b_fm     = (const float*)d_in[6];
    const float* W1       = (const float*)d_in[7];
    const float* b1       = (const float*)d_in[8];
    const float* W2       = (const float*)d_in[9];
    const float* b2       = (const float*)d_in[10];
    const float* W3       = (const float*)d_in[11];
    const float* b3       = (const float*)d_in[12];
    float* out = (float*)d_out;
    (void)ws_size; (void)in_sizes; (void)n_in; (void)out_size;

    char* ws = (char*)d_ws;
    float*    yfm    = (float*)   (ws + WS_YFM_OFF);
    float*    ydeep  = (float*)   (ws + WS_YDEEP_OFF);
    ushort_t* embedB = (ushort_t*)(ws + WS_EMBED_OFF);
    ushort_t* h1B    = (ushort_t*)(ws + WS_H1_OFF);
    ushort_t* W1t    = (ushort_t*)(ws + WS_W1T_OFF);
    ushort_t* W2t    = (ushort_t*)(ws + WS_W2T_OFF);

    // A+B) fused scan + assemble, with weight prep riding along in extra blocks
    scan_prep_kernel<<<BATCH + PREP_BLOCKS, 256, 0, stream>>>(
        cat, numeric, W_num, b_num, emb_tab, w_fm, b_fm, embedB, yfm,
        W1, W2, W1t, W2t, ydeep);
    // C) h1 = relu(embed @ W1 + b1) -> bf16
    {
        dim3 grid(H1 / 64, BATCH / 64);
        gemm1_kernel<<<grid, 256, 0, stream>>>(embedB, W1t, b1, h1B);
    }
    // D) ydeep += partial dots of relu(h1 @ W2 + b2) with W3
    {
        dim3 grid(H2 / 64, BATCH / 32);
        gemm2_dot_kernel<<<grid, 256, 0, stream>>>(h1B, W2t, b2, W3, ydeep);
    }
    // E) out = sigmoid(yfm + relu(ydeep + b3))
    final_kernel<<<BATCH / 256, 256, 0, stream>>>(yfm, ydeep, b3, out);
}

// Round 5
// 554.735 us; speedup vs baseline: 1.0739x; 1.0739x over previous
//
#include <hip/hip_runtime.h>
#include <math.h>

// ---------------- problem constants ----------------
#define BATCH   4096
#define NUM     13
#define NCAT    26
#define VOCAB   1000
#define EMB     16
#define DEMBED  624      // NUM*EMB + NCAT*EMB = 208 + 416
#define KPAD    640      // DEMBED padded to multiple of 64 for BK=64 MFMA loop
#define H1      512
#define H2      256

#define LDS_STRIDE 72    // 64 + 8 ushorts pad: 144 B rows, 2-way max conflict (free)

typedef unsigned short ushort_t;
typedef __attribute__((ext_vector_type(8))) short bf16x8;
typedef __attribute__((ext_vector_type(4))) float f32x4;

// ---------------- workspace layout (bytes) ----------------
#define WS_YFM_OFF    0                                    // f32  4096      = 16384
#define WS_YDEEP_OFF  (WS_YFM_OFF + BATCH * 4)             // f32  4096      = 16384
#define WS_EMBED_OFF  (WS_YDEEP_OFF + BATCH * 4)           // bf16 4096*640  = 5242880
#define WS_H1_OFF     (WS_EMBED_OFF + BATCH * KPAD * 2)    // bf16 4096*512  = 4194304
#define WS_W1T_OFF    (WS_H1_OFF + BATCH * H1 * 2)         // bf16 512*640   = 655360
#define WS_W2T_OFF    (WS_W1T_OFF + H1 * KPAD * 2)         // bf16 256*512   = 262144

__device__ __forceinline__ ushort_t f2bf(float f) {
    union { float f; unsigned int u; } v; v.f = f;
    unsigned int r = v.u + 0x7FFFu + ((v.u >> 16) & 1u);   // round-nearest-even
    return (ushort_t)(r >> 16);
}

// ---------------------------------------------------------------------------
// Kernel A+B merged: blocks [0, BATCH) do the fused one-hot scan + assembly
// (one block per sample); blocks [BATCH, ...) do weight prep (W1/W2
// cast+transpose, ydeep zero-init).
//
// Scan: BREADTH-FIRST across each wave's 6-7 categories at 128-elem (512 B)
// granularity. Per phase: issue one float2 load per UNFOUND category (all
// independent, 6-7 in flight), then ballot-check each. Bytes/latency are
// decoupled: E[bytes] = 0.565 * 426 MB = 241 MB, ~7 pipelined phase
// latencies per wave, hidden by TLP.
// NOTE (R4 lesson): g=64 cut bytes to 227 MB but doubled serial phases
// (E[max over 6.5 labels] governs) -> +37 us. g=128 is the sweet spot.
// ---------------------------------------------------------------------------
#define PREP_N1 (H1 * KPAD)          // 327680
#define PREP_N2 (H2 * H1)            // 131072
#define PREP_N3 (BATCH)              // ydeep zeroes
#define PREP_TOTAL (PREP_N1 + PREP_N2 + PREP_N3)
#define PREP_BLOCKS ((PREP_TOTAL + 255) / 256)

__global__ __launch_bounds__(256) void scan_prep_kernel(
    const float* __restrict__ cat,
    const float* __restrict__ numeric, const float* __restrict__ W_num,
    const float* __restrict__ b_num, const float* __restrict__ emb_tables,
    const float* __restrict__ w_fm, const float* __restrict__ b_fm,
    ushort_t* __restrict__ embedB, float* __restrict__ yfm,
    const float* __restrict__ W1, const float* __restrict__ W2,
    ushort_t* __restrict__ W1t, ushort_t* __restrict__ W2t,
    float* __restrict__ ydeep)
{
    __shared__ float es[DEMBED];
    __shared__ int   lab[NCAT];
    __shared__ float red[EMB];
    __shared__ float sp[NCAT + NUM];

    int tid = threadIdx.x;

    // ---------------- prep blocks ----------------
    if (blockIdx.x >= BATCH) {
        int t = (blockIdx.x - BATCH) * 256 + tid;
        if (t < PREP_N1) {
            int n = t / KPAD, kp = t - n * KPAD;
            float v = (kp < DEMBED) ? W1[(size_t)kp * H1 + n] : 0.f;
            W1t[t] = f2bf(v);
        } else if (t < PREP_N1 + PREP_N2) {
            int u = t - PREP_N1;
            int n = u >> 9, k = u & 511;
            W2t[u] = f2bf(W2[(size_t)k * H2 + n]);
        } else if (t < PREP_TOTAL) {
            ydeep[t - PREP_N1 - PREP_N2] = 0.f;
        }
        return;
    }

    // ---------------- scan blocks ----------------
    int b    = blockIdx.x;
    int w    = tid >> 6;
    int lane = tid & 63;

    // wave w owns cats {w, w+4, w+8, ...}: 7 for w<2, 6 for w>=2
    {
        const int nc = (w < 2) ? 7 : 6;
        int labf[7];
#pragma unroll
        for (int i = 0; i < 7; ++i) labf[i] = -1;
        unsigned mask = (1u << nc) - 1;      // unfound cats (wave-uniform)

        for (int p = 0; p < 8 && mask; ++p) {
            float2 v[7];
            int i2 = p * 64 + lane;          // float2 index within row
#pragma unroll
            for (int i = 0; i < 7; ++i) {
                if (i < nc && ((mask >> i) & 1)) {
                    int c = w + 4 * i;
                    const float2* src =
                        (const float2*)(cat + ((size_t)b * NCAT + c) * VOCAB);
                    v[i] = (i2 < VOCAB / 2) ? src[i2] : (float2){0.f, 0.f};
                }
            }
#pragma unroll
            for (int i = 0; i < 7; ++i) {
                if (i < nc && ((mask >> i) & 1)) {
                    int base = i2 * 2;
                    int f = -1;
                    if (v[i].x > 0.5f) f = base;
                    if (v[i].y > 0.5f) f = base + 1;
                    unsigned long long bal = __ballot(f >= 0);
                    if (bal) {
                        int src_lane = (int)__ffsll((unsigned long long)bal) - 1;
                        labf[i] = __shfl(f, src_lane);
                        mask &= ~(1u << i);
                    }
                }
            }
        }
        if (lane == 0) {
#pragma unroll
            for (int i = 0; i < 7; ++i)
                if (i < nc) lab[w + 4 * i] = (labf[i] < 0) ? 0 : labf[i];
        }
    }
    __syncthreads();

    // ---- assemble embed row (bf16, KPAD wide) ----
    ushort_t* eout = embedB + (size_t)b * KPAD;
    for (int t = tid; t < KPAD; t += 256) {
        float v = 0.f;
        if (t < NUM * EMB) {
            int j = t >> 4;
            v = numeric[b * NUM + j] * W_num[t] + b_num[t];
        } else if (t < DEMBED) {
            int u = t - NUM * EMB;
            int c = u >> 4, k = u & 15;
            v = emb_tables[((size_t)c * VOCAB + lab[c]) * EMB + k];
        }
        if (t < DEMBED) es[t] = v;
        eout[t] = f2bf(v);
    }
    // parallel sparse-FM gathers
    if (tid < NCAT) {
        sp[tid] = w_fm[NUM + tid * VOCAB + lab[tid]];
    } else if (tid < NCAT + NUM) {
        int j = tid - NCAT;
        sp[tid] = numeric[b * NUM + j] * w_fm[j];
    }
    __syncthreads();

    if (tid < EMB) {
        float ns = 0.f, cs = 0.f;
        for (int j = 0; j < NUM; ++j)  ns += es[j * EMB + tid];
        for (int c = 0; c < NCAT; ++c) cs += es[NUM * EMB + c * EMB + tid];
        red[tid] = ns * cs;
    }
    __syncthreads();

    if (tid == 0) {
        float y = b_fm[0];
        for (int k = 0; k < EMB; ++k)          y += red[k];
        for (int i = 0; i < NCAT + NUM; ++i)   y += sp[i];
        yfm[b] = y;
    }
}

// ---------------------------------------------------------------------------
// Kernel C: MFMA bf16 GEMM1: h1 = relu(embed @ W1t^T + b1) -> bf16.
// 64x64 tile, BK=64, 4 waves (2x2), each wave 32x32 via 2x2 mfma 16x16x32.
// k+1 global loads issued after the second barrier (overlap the MFMA phase).
// Fragment layouts (HW-verified):
//   A/B-op: lane holds X[m=lane&15][k=(lane>>4)*8 + j], j=0..7
//   C/D   : col=lane&15, row=(lane>>4)*4 + reg
// ---------------------------------------------------------------------------
__global__ __launch_bounds__(256) void gemm1_kernel(
    const ushort_t* __restrict__ A, const ushort_t* __restrict__ Bt,
    const float* __restrict__ bias, ushort_t* __restrict__ Cout)
{
    const int N = H1, K = KPAD;
    __shared__ ushort_t As[64 * LDS_STRIDE];
    __shared__ ushort_t Bs[64 * LDS_STRIDE];

    int tid = threadIdx.x;
    int l   = tid & 63;
    int w   = tid >> 6;
    int wm  = w >> 1, wn = w & 1;
    int bm  = blockIdx.y * 64;
    int bn  = blockIdx.x * 64;

    int srow = tid >> 2;
    int sk   = (tid & 3) * 8;

    const ushort_t* ap = &A [(size_t)(bm + srow) * K + sk];
    const ushort_t* bp = &Bt[(size_t)(bn + srow) * K + sk];

    // prologue: prefetch k0 = 0
    uint4 av0 = *(const uint4*)ap;
    uint4 av1 = *(const uint4*)(ap + 32);
    uint4 bv0 = *(const uint4*)bp;
    uint4 bv1 = *(const uint4*)(bp + 32);

    f32x4 acc[2][2];
#pragma unroll
    for (int i = 0; i < 2; ++i)
#pragma unroll
        for (int j = 0; j < 2; ++j)
            acc[i][j] = (f32x4){0.f, 0.f, 0.f, 0.f};

    for (int k0 = 0; k0 < K; k0 += 64) {
        __syncthreads();                      // LDS free (prev iter reads done)
        *(uint4*)&As[srow * LDS_STRIDE + sk]      = av0;
        *(uint4*)&As[srow * LDS_STRIDE + sk + 32] = av1;
        *(uint4*)&Bs[srow * LDS_STRIDE + sk]      = bv0;
        *(uint4*)&Bs[srow * LDS_STRIDE + sk + 32] = bv1;
        __syncthreads();

        if (k0 + 64 < K) {                    // prefetch k+1 under MFMA phase
            av0 = *(const uint4*)(ap + k0 + 64);
            av1 = *(const uint4*)(ap + k0 + 96);
            bv0 = *(const uint4*)(bp + k0 + 64);
            bv1 = *(const uint4*)(bp + k0 + 96);
        }

#pragma unroll
        for (int s = 0; s < 2; ++s) {
            bf16x8 af[2], bfr[2];
#pragma unroll
            for (int i = 0; i < 2; ++i)
                af[i] = *(const bf16x8*)&As[(wm * 32 + i * 16 + (l & 15)) * LDS_STRIDE
                                            + s * 32 + (l >> 4) * 8];
#pragma unroll
            for (int j = 0; j < 2; ++j)
                bfr[j] = *(const bf16x8*)&Bs[(wn * 32 + j * 16 + (l & 15)) * LDS_STRIDE
                                             + s * 32 + (l >> 4) * 8];
#pragma unroll
            for (int i = 0; i < 2; ++i)
#pragma unroll
                for (int j = 0; j < 2; ++j)
                    acc[i][j] = __builtin_amdgcn_mfma_f32_16x16x32_bf16(
                        af[i], bfr[j], acc[i][j], 0, 0, 0);
        }
    }

#pragma unroll
    for (int i = 0; i < 2; ++i) {
        int row0 = bm + wm * 32 + i * 16 + (l >> 4) * 4;
#pragma unroll
        for (int j = 0; j < 2; ++j) {
            int col = bn + wn * 32 + j * 16 + (l & 15);
            float bv = bias[col];
#pragma unroll
            for (int r = 0; r < 4; ++r) {
                float v = fmaxf(acc[i][j][r] + bv, 0.f);
                Cout[(size_t)(row0 + r) * N + col] = f2bf(v);
            }
        }
    }
}

// ---------------------------------------------------------------------------
// Kernel D: fused GEMM2 + W3 dot. h2 never materializes.
// 32x64 tile (grid 4 x 128 = 512 blocks), BK=64, 4 waves:
// wave w: row-tile i=w>>1 (16 rows), cols (w&1)*32 + 2x16.
// k+1 prefetch-under-MFMA as gemm1.
// Epilogue: s = sum_j relu(acc+b2)*W3[col]; 16-lane shuffle-reduce;
// atomicAdd into ydeep[row] (zeroed by prep). ReLU is per-element of h2,
// so N-split partial dots are exact.
// ---------------------------------------------------------------------------
__global__ __launch_bounds__(256) void gemm2_dot_kernel(
    const ushort_t* __restrict__ A, const ushort_t* __restrict__ Bt,
    const float* __restrict__ bias, const float* __restrict__ W3,
    float* __restrict__ ydeep)
{
    const int K = H1;
    __shared__ ushort_t As[32 * LDS_STRIDE];
    __shared__ ushort_t Bs[64 * LDS_STRIDE];

    int tid = threadIdx.x;
    int l   = tid & 63;
    int w   = tid >> 6;
    int it  = w >> 1;               // row-tile index (0..1)
    int cb  = (w & 1) * 32;         // col base within tile
    int bm  = blockIdx.y * 32;
    int bn  = blockIdx.x * 64;

    int srow = tid >> 3;            // 0..31
    int sk   = (tid & 7) * 8;       // 0..56

    const ushort_t* ap  = &A [(size_t)(bm + srow) * K + sk];
    const ushort_t* bp0 = &Bt[(size_t)(bn + srow) * K + sk];
    const ushort_t* bp1 = &Bt[(size_t)(bn + srow + 32) * K + sk];

    uint4 av  = *(const uint4*)ap;
    uint4 bv0 = *(const uint4*)bp0;
    uint4 bv1 = *(const uint4*)bp1;

    f32x4 acc[2];
    acc[0] = (f32x4){0.f, 0.f, 0.f, 0.f};
    acc[1] = (f32x4){0.f, 0.f, 0.f, 0.f};

    for (int k0 = 0; k0 < K; k0 += 64) {
        __syncthreads();
        *(uint4*)&As[srow * LDS_STRIDE + sk]        = av;
        *(uint4*)&Bs[srow * LDS_STRIDE + sk]        = bv0;
        *(uint4*)&Bs[(srow + 32) * LDS_STRIDE + sk] = bv1;
        __syncthreads();

        if (k0 + 64 < K) {                    // prefetch k+1 under MFMA phase
            av  = *(const uint4*)(ap  + k0 + 64);
            bv0 = *(const uint4*)(bp0 + k0 + 64);
            bv1 = *(const uint4*)(bp1 + k0 + 64);
        }

#pragma unroll
        for (int s = 0; s < 2; ++s) {
            bf16x8 af = *(const bf16x8*)&As[(it * 16 + (l & 15)) * LDS_STRIDE
                                            + s * 32 + (l >> 4) * 8];
#pragma unroll
            for (int j = 0; j < 2; ++j) {
                bf16x8 bfr = *(const bf16x8*)&Bs[(cb + j * 16 + (l & 15)) * LDS_STRIDE
                                                 + s * 32 + (l >> 4) * 8];
                acc[j] = __builtin_amdgcn_mfma_f32_16x16x32_bf16(af, bfr, acc[j], 0, 0, 0);
            }
        }
    }

    // epilogue: partial dot with W3 over this wave's 32 cols
    int row0 = bm + it * 16 + (l >> 4) * 4;
    float w3v[2], b2v[2];
#pragma unroll
    for (int j = 0; j < 2; ++j) {
        int col = bn + cb + j * 16 + (l & 15);
        w3v[j] = W3[col];
        b2v[j] = bias[col];
    }
#pragma unroll
    for (int r = 0; r < 4; ++r) {
        float s = fmaxf(acc[0][r] + b2v[0], 0.f) * w3v[0]
                + fmaxf(acc[1][r] + b2v[1], 0.f) * w3v[1];
#pragma unroll
        for (int off = 8; off > 0; off >>= 1)
            s += __shfl_xor(s, off);
        if ((l & 15) == 0)
            atomicAdd(&ydeep[row0 + r], s);
    }
}

// ---------------------------------------------------------------------------
// Kernel E: final: out = sigmoid(yfm + relu(ydeep + b3))
// ---------------------------------------------------------------------------
__global__ __launch_bounds__(256) void final_kernel(
    const float* __restrict__ yfm, const float* __restrict__ ydeep,
    const float* __restrict__ b3, float* __restrict__ out)
{
    int b = blockIdx.x * 256 + threadIdx.x;
    if (b >= BATCH) return;
    float yd = fmaxf(ydeep[b] + b3[0], 0.f);
    float x  = yfm[b] + yd;
    out[b] = 1.f / (1.f + expf(-x));
}

// ---------------------------------------------------------------------------
extern "C" void kernel_launch(void* const* d_in, const int* in_sizes, int n_in,
                              void* d_out, int out_size, void* d_ws, size_t ws_size,
                              hipStream_t stream)
{
    const float* numeric  = (const float*)d_in[0];
    const float* cat      = (const float*)d_in[1];
    const float* W_num    = (const float*)d_in[2];
    const float* b_num    = (const float*)d_in[3];
    const float* emb_tab  = (const float*)d_in[4];
    const float* w_fm     = (const float*)d_in[5];
    const float* b_fm     = (const float*)d_in[6];
    const float* W1       = (const float*)d_in[7];
    const float* b1       = (const float*)d_in[8];
    const float* W2       = (const float*)d_in[9];
    const float* b2       = (const float*)d_in[10];
    const float* W3       = (const float*)d_in[11];
    const float* b3       = (const float*)d_in[12];
    float* out = (float*)d_out;
    (void)ws_size; (void)in_sizes; (void)n_in; (void)out_size;

    char* ws = (char*)d_ws;
    float*    yfm    = (float*)   (ws + WS_YFM_OFF);
    float*    ydeep  = (float*)   (ws + WS_YDEEP_OFF);
    ushort_t* embedB = (ushort_t*)(ws + WS_EMBED_OFF);
    ushort_t* h1B    = (ushort_t*)(ws + WS_H1_OFF);
    ushort_t* W1t    = (ushort_t*)(ws + WS_W1T_OFF);
    ushort_t* W2t    = (ushort_t*)(ws + WS_W2T_OFF);

    // A+B) fused scan + assemble, with weight prep riding along in extra blocks
    scan_prep_kernel<<<BATCH + PREP_BLOCKS, 256, 0, stream>>>(
        cat, numeric, W_num, b_num, emb_tab, w_fm, b_fm, embedB, yfm,
        W1, W2, W1t, W2t, ydeep);
    // C) h1 = relu(embed @ W1 + b1) -> bf16
    {
        dim3 grid(H1 / 64, BATCH / 64);
        gemm1_kernel<<<grid, 256, 0, stream>>>(embedB, W1t, b1, h1B);
    }
    // D) ydeep += partial dots of relu(h1 @ W2 + b2) with W3
    {
        dim3 grid(H2 / 64, BATCH / 32);
        gemm2_dot_kernel<<<grid, 256, 0, stream>>>(h1B, W2t, b2, W3, ydeep);
    }
    // E) out = sigmoid(yfm + relu(ydeep + b3))
    final_kernel<<<BATCH / 256, 256, 0, stream>>>(yfm, ydeep, b3, out);
}